// Round 1
// baseline (1048.800 us; speedup 1.0000x reference)
//
#include <hip/hip_runtime.h>
#include <math.h>

// Problem constants (fixed by setup_inputs)
// B=32, S=256, NU=4, ML=9, H=768, V=30522; T = NU*ML = 36; M = B*T = 1152.
#define BB_ 32
#define SS_ 256
#define HH_ 768
#define VV_ 30522
#define TT_ 36
#define MM_ 1152

typedef __bf16 bf16x8 __attribute__((ext_vector_type(8)));
typedef __bf16 bf16x4 __attribute__((ext_vector_type(4)));
typedef float f32x4 __attribute__((ext_vector_type(4)));

__device__ __forceinline__ float sigmoidf_(float x) { return 1.f / (1.f + expf(-x)); }

// ---------------- fp32 -> bf16 bulk convert (float4 -> bf16x4) ----------------
__global__ __launch_bounds__(256) void cvt_bf16(const float* __restrict__ s,
                                                __bf16* __restrict__ d, int n4) {
  int i = blockIdx.x * 256 + threadIdx.x;
  if (i < n4) {
    float4 v = reinterpret_cast<const float4*>(s)[i];
    bf16x4 o;
    o[0] = (__bf16)v.x; o[1] = (__bf16)v.y; o[2] = (__bf16)v.z; o[3] = (__bf16)v.w;
    reinterpret_cast<bf16x4*>(d)[i] = o;
  }
}

// ---------------- build step inputs ws[tau*32+b][k] (bf16) ----------------
__global__ __launch_bounds__(256) void build_ws(const float* __restrict__ dec,   // [B][NU][H]
                                                const int* __restrict__ teacher, // [B][NU][ML]
                                                const float* __restrict__ embed, // [V][H]
                                                __bf16* __restrict__ wsbf) {
  int idx = blockIdx.x * 256 + threadIdx.x;
  if (idx >= MM_ * HH_) return;
  int m = idx / HH_, k = idx - m * HH_;   // m = tau*32 + b
  int tau = m >> 5, b = m & 31;
  int u = tau / 9, tt = tau - u * 9;
  float v;
  if (tt == 0) v = dec[((size_t)b * 4 + u) * HH_ + k];
  else v = embed[(size_t)teacher[(b * 4 + u) * 9 + tt - 1] * HH_ + k];
  wsbf[idx] = (__bf16)v;
}

// ---------------- encg[b][s] = enc[b][s][:] . wgen[1536:2304] ----------------
__global__ __launch_bounds__(256) void enc_gate(const float* __restrict__ enc,
                                                const float* __restrict__ wgen,
                                                float* __restrict__ encg) {
  int row = blockIdx.x * 4 + (threadIdx.x >> 6);  // 0..8191 = b*256+s
  int lane = threadIdx.x & 63;
  const float* er = enc + (size_t)row * HH_;
  float ssum = 0.f;
#pragma unroll
  for (int i = 0; i < 12; ++i) ssum += er[i * 64 + lane] * wgen[1536 + i * 64 + lane];
  for (int off = 32; off; off >>= 1) ssum += __shfl_down(ssum, off);
  if (lane == 0) encg[row] = ssum;
}

// ---------------- generic bf16 MFMA GEMM: C[M][ldC] = A[M][768] * B[N][768]^T ----------------
// grid = (ceil(N/128), M/128), block = 256. B rows clamped to Nreal; store guarded.
__global__ __launch_bounds__(256) void gemm_bt(const __bf16* __restrict__ A,
                                               const __bf16* __restrict__ Bm,
                                               float* __restrict__ C,
                                               int Nreal, int ldC) {
  __shared__ __bf16 As[128 * 32];
  __shared__ __bf16 Bs[128 * 32];
  const int tid = threadIdx.x;
  const int lane = tid & 63, wave = tid >> 6;
  const int wm = wave >> 1, wn = wave & 1;
  const int q = lane >> 4, ln = lane & 15;
  const int m0 = blockIdx.y * 128, n0 = blockIdx.x * 128;
  f32x4 acc[4][4] = {};
  for (int kb = 0; kb < 24; ++kb) {
    const int k0 = kb * 32;
#pragma unroll
    for (int i = 0; i < 2; ++i) {
      int c = tid + i * 256;
      int row = c >> 2, kc = c & 3;
      bf16x8 va = *reinterpret_cast<const bf16x8*>(A + (size_t)(m0 + row) * HH_ + k0 + kc * 8);
      *reinterpret_cast<bf16x8*>(&As[row * 32 + kc * 8]) = va;
      int brow = n0 + row; if (brow >= Nreal) brow = Nreal - 1;
      bf16x8 vb = *reinterpret_cast<const bf16x8*>(Bm + (size_t)brow * HH_ + k0 + kc * 8);
      *reinterpret_cast<bf16x8*>(&Bs[row * 32 + kc * 8]) = vb;
    }
    __syncthreads();
    bf16x8 af[4], bfr[4];
#pragma unroll
    for (int mi = 0; mi < 4; ++mi)
      af[mi] = *reinterpret_cast<const bf16x8*>(&As[(wm * 64 + mi * 16 + ln) * 32 + q * 8]);
#pragma unroll
    for (int ni = 0; ni < 4; ++ni)
      bfr[ni] = *reinterpret_cast<const bf16x8*>(&Bs[(wn * 64 + ni * 16 + ln) * 32 + q * 8]);
#pragma unroll
    for (int mi = 0; mi < 4; ++mi)
#pragma unroll
      for (int ni = 0; ni < 4; ++ni)
        acc[mi][ni] = __builtin_amdgcn_mfma_f32_16x16x32_bf16(af[mi], bfr[ni], acc[mi][ni], 0, 0, 0);
    __syncthreads();
  }
#pragma unroll
  for (int mi = 0; mi < 4; ++mi)
#pragma unroll
    for (int ni = 0; ni < 4; ++ni) {
      int n = n0 + wn * 64 + ni * 16 + ln;
      if (n < Nreal) {
#pragma unroll
        for (int r2 = 0; r2 < 4; ++r2) {
          int m = m0 + wm * 64 + mi * 16 + q * 4 + r2;
          C[(size_t)m * ldC + n] = acc[mi][ni][r2];
        }
      }
    }
}

// ---------------- one GRU step: gh = h @ Whh^T via MFMA, gates in-lane ----------------
// grid = 24 wgs x 256. wave = (mi, nh). Each wave: 3 accs = gates r/z/n for its 16 j's.
__global__ __launch_bounds__(256) void gru_step(const __bf16* __restrict__ Aprev, // rows b at stride
                                                size_t prev_stride,
                                                const float* __restrict__ Hprev,  // [b][768] fp32
                                                const __bf16* __restrict__ Whh,   // [2304][768]
                                                const float* __restrict__ GIt,    // GI + tau*32*2304
                                                const float* __restrict__ bih,
                                                const float* __restrict__ bhh,
                                                float* __restrict__ Hout,         // [b][768]
                                                __bf16* __restrict__ Ah, int tau) {
  const int tid = threadIdx.x, lane = tid & 63, wave = tid >> 6;
  const int mi = wave >> 1, nh = wave & 1;
  const int q = lane >> 4, ln = lane & 15;
  const int jH = blockIdx.x * 32 + nh * 16 + ln;
  const __bf16* arow = Aprev + (size_t)(mi * 16 + ln) * prev_stride;
  const __bf16* brow0 = Whh + (size_t)jH * HH_;
  const __bf16* brow1 = Whh + (size_t)(jH + 768) * HH_;
  const __bf16* brow2 = Whh + (size_t)(jH + 1536) * HH_;
  f32x4 acc0 = {}, acc1 = {}, acc2 = {};
#pragma unroll 4
  for (int kb = 0; kb < 24; ++kb) {
    int k0 = kb * 32 + q * 8;
    bf16x8 a = *reinterpret_cast<const bf16x8*>(arow + k0);
    bf16x8 b0 = *reinterpret_cast<const bf16x8*>(brow0 + k0);
    bf16x8 b1 = *reinterpret_cast<const bf16x8*>(brow1 + k0);
    bf16x8 b2 = *reinterpret_cast<const bf16x8*>(brow2 + k0);
    acc0 = __builtin_amdgcn_mfma_f32_16x16x32_bf16(a, b0, acc0, 0, 0, 0);
    acc1 = __builtin_amdgcn_mfma_f32_16x16x32_bf16(a, b1, acc1, 0, 0, 0);
    acc2 = __builtin_amdgcn_mfma_f32_16x16x32_bf16(a, b2, acc2, 0, 0, 0);
  }
  float bihr = bih[jH], bihz = bih[jH + 768], bihn = bih[jH + 1536];
  float bhhr = bhh[jH], bhhz = bhh[jH + 768], bhhn = bhh[jH + 1536];
#pragma unroll
  for (int r2 = 0; r2 < 4; ++r2) {
    int b = mi * 16 + q * 4 + r2;
    const float* gi = GIt + (size_t)b * 2304;
    float ir = gi[jH] + bihr;
    float iz = gi[jH + 768] + bihz;
    float in_ = gi[jH + 1536] + bihn;
    float hr = acc0[r2] + bhhr;
    float hz = acc1[r2] + bhhz;
    float hn = acc2[r2] + bhhn;
    float r = sigmoidf_(ir + hr);
    float z = sigmoidf_(iz + hz);
    float n = tanhf(in_ + r * hn);
    float hp = Hprev[(size_t)b * HH_ + jH];
    float h = (1.f - z) * n + z * hp;
    Hout[(size_t)b * HH_ + jH] = h;
    Ah[((size_t)b * TT_ + tau) * HH_ + jH] = (__bf16)h;
  }
}

// ---------------- attention scores E[b*36+tau][s] = h . enc[b][s] (batched MFMA) ----------------
// grid = 32*4 wgs x 256. wg = (b, s-tile of 64); wave = 16 s; 3 m-tiles cover tau 0..47 (clamped).
__global__ __launch_bounds__(256) void attn_gemm(const __bf16* __restrict__ Ah,
                                                 const __bf16* __restrict__ encb,
                                                 float* __restrict__ E) {
  int b = blockIdx.x >> 2, stile = blockIdx.x & 3;
  int wave = threadIdx.x >> 6, lane = threadIdx.x & 63;
  int q = lane >> 4, ln = lane & 15;
  int s = stile * 64 + wave * 16 + ln;
  const __bf16* brow = encb + ((size_t)b * SS_ + s) * HH_;
  const __bf16* arow[3];
#pragma unroll
  for (int mt = 0; mt < 3; ++mt) {
    int tau = mt * 16 + ln; if (tau > 35) tau = 35;
    arow[mt] = Ah + ((size_t)b * TT_ + tau) * HH_;
  }
  f32x4 acc[3] = {};
#pragma unroll 4
  for (int kb = 0; kb < 24; ++kb) {
    int k0 = kb * 32 + q * 8;
    bf16x8 bb = *reinterpret_cast<const bf16x8*>(brow + k0);
#pragma unroll
    for (int mt = 0; mt < 3; ++mt) {
      bf16x8 aa = *reinterpret_cast<const bf16x8*>(arow[mt] + k0);
      acc[mt] = __builtin_amdgcn_mfma_f32_16x16x32_bf16(aa, bb, acc[mt], 0, 0, 0);
    }
  }
#pragma unroll
  for (int mt = 0; mt < 3; ++mt)
#pragma unroll
    for (int r2 = 0; r2 < 4; ++r2) {
      int tau = mt * 16 + q * 4 + r2;
      if (tau < 36) E[((size_t)b * TT_ + tau) * SS_ + s] = acc[mt][r2];
    }
}

// ---------------- masked softmax over S + p_gen ----------------
__global__ __launch_bounds__(256) void softmax_pg(const float* __restrict__ E,
                                                  const int* __restrict__ x,
                                                  const float* __restrict__ encg,
                                                  const __bf16* __restrict__ wsbf,
                                                  const __bf16* __restrict__ Ah,
                                                  const float* __restrict__ wgen,
                                                  const float* __restrict__ wgenb,
                                                  float* __restrict__ attn,
                                                  float* __restrict__ pg) {
  int m = blockIdx.x;               // b*36 + tau
  int b = m / TT_, tau = m - b * TT_;
  int m_in = tau * 32 + b;
  int t = threadIdx.x;
  __shared__ float red[256];
  __shared__ float r1[256], r2[256], r3[256];
  float e = E[(size_t)m * SS_ + t];
  if (x[b * SS_ + t] == 0) e = -1000000000.0f;
  red[t] = e; __syncthreads();
  for (int off = 128; off; off >>= 1) {
    if (t < off) red[t] = fmaxf(red[t], red[t + off]);
    __syncthreads();
  }
  float mx = red[0];
  float p = expf(e - mx);
  float dsum = 0.f;
#pragma unroll
  for (int i = 0; i < 3; ++i) {
    int k = t + i * 256;
    dsum += (float)wsbf[(size_t)m_in * HH_ + k] * wgen[k];
    dsum += (float)Ah[(size_t)m * HH_ + k] * wgen[768 + k];
  }
  float pe = p * encg[b * SS_ + t];
  r1[t] = p; r2[t] = pe; r3[t] = dsum; __syncthreads();
  for (int off = 128; off; off >>= 1) {
    if (t < off) { r1[t] += r1[t + off]; r2[t] += r2[t + off]; r3[t] += r3[t + off]; }
    __syncthreads();
  }
  float Z = r1[0];
  attn[(size_t)m * SS_ + t] = p / Z;
  if (t == 0) pg[m] = sigmoidf_(r3[0] + r2[0] / Z + wgenb[0]);
}

// ---------------- per-row max & sum(exp) over vocab logits ----------------
__global__ __launch_bounds__(256) void rowstat(const float* __restrict__ C,
                                               float* __restrict__ rm, float* __restrict__ rs) {
  int m = blockIdx.x, t = threadIdx.x;
  const float* row = C + (size_t)m * VV_;
  float mx = -1e30f, s = 0.f;
  for (int i = t; i < VV_; i += 256) {
    float v = row[i];
    float nm = fmaxf(mx, v);
    s = s * expf(mx - nm) + expf(v - nm);
    mx = nm;
  }
  __shared__ float sm[256], ss[256];
  sm[t] = mx; ss[t] = s; __syncthreads();
  for (int off = 128; off; off >>= 1) {
    if (t < off) {
      float m2 = sm[t + off], s2 = ss[t + off];
      float M = fmaxf(sm[t], m2);
      ss[t] = ss[t] * expf(sm[t] - M) + s2 * expf(m2 - M);
      sm[t] = M;
    }
    __syncthreads();
  }
  if (t == 0) { rm[m] = sm[0]; rs[m] = ss[0]; }
}

// ---------------- finalize: out = pg * softmax(logits) (in-place) ----------------
__global__ __launch_bounds__(256) void finalize(float* __restrict__ C,
                                                const float* __restrict__ rm,
                                                const float* __restrict__ rs,
                                                const float* __restrict__ pg) {
  int m = blockIdx.y;
  int i = blockIdx.x * 256 + threadIdx.x;
  if (i < VV_) {
    size_t idx = (size_t)m * VV_ + i;
    C[idx] = pg[m] * expf(C[idx] - rm[m]) / rs[m];
  }
}

// ---------------- pointer scatter: out[m][x[b][s]] += (1-pg)*attn[m][s] ----------------
__global__ __launch_bounds__(256) void scatter_ctx(float* __restrict__ C,
                                                   const float* __restrict__ attn,
                                                   const float* __restrict__ pg,
                                                   const int* __restrict__ x) {
  int m = blockIdx.x, s = threadIdx.x;
  int b = m / TT_;
  float v = (1.f - pg[m]) * attn[(size_t)m * SS_ + s];
  int col = x[b * SS_ + s];
  atomicAdd(C + (size_t)m * VV_ + col, v);
}

extern "C" void kernel_launch(void* const* d_in, const int* in_sizes, int n_in,
                              void* d_out, int out_size, void* d_ws, size_t ws_size,
                              hipStream_t stream) {
  const int*   x       = (const int*)d_in[0];
  const float* dec     = (const float*)d_in[1];
  const float* enc     = (const float*)d_in[2];
  const float* hidden  = (const float*)d_in[3];
  const int*   teacher = (const int*)d_in[5];
  const float* embed   = (const float*)d_in[6];
  const float* wih     = (const float*)d_in[7];
  const float* whh     = (const float*)d_in[8];
  const float* bih     = (const float*)d_in[9];
  const float* bhh     = (const float*)d_in[10];
  const float* wgen    = (const float*)d_in[11];
  const float* wgenb   = (const float*)d_in[12];
  float* out = (float*)d_out;

  // workspace layout (all sizes 256B-aligned); total ~85.8 MB
  char* w = (char*)d_ws;
  __bf16* embed_bf = (__bf16*)w;  w += (size_t)VV_ * HH_ * 2;          // 46,881,792
  __bf16* enc_bf   = (__bf16*)w;  w += (size_t)BB_ * SS_ * HH_ * 2;    // 12,582,912
  __bf16* wih_bf   = (__bf16*)w;  w += (size_t)2304 * HH_ * 2;         //  3,538,944
  __bf16* whh_bf   = (__bf16*)w;  w += (size_t)2304 * HH_ * 2;         //  3,538,944
  __bf16* ws_bf    = (__bf16*)w;  w += (size_t)MM_ * HH_ * 2;          //  1,769,472
  __bf16* hid_bf   = (__bf16*)w;  w += (size_t)BB_ * HH_ * 2;          //     49,152
  __bf16* A_h      = (__bf16*)w;  w += (size_t)MM_ * HH_ * 2;          //  1,769,472
  float*  H_all    = (float*)w;   w += (size_t)TT_ * BB_ * HH_ * 4;    //  3,538,944
  float*  GI       = (float*)w;   w += (size_t)MM_ * 2304 * 4;         // 10,616,832
  float*  E        = (float*)w;   w += (size_t)MM_ * SS_ * 4;          //  1,179,648
  float*  attn     = (float*)w;   w += (size_t)MM_ * SS_ * 4;          //  1,179,648
  float*  encg     = (float*)w;   w += (size_t)BB_ * SS_ * 4;          //     32,768
  float*  pg       = (float*)w;   w += 8192;
  float*  rm       = (float*)w;   w += 8192;
  float*  rs       = (float*)w;   w += 8192;

  // 1) conversions to bf16
  cvt_bf16<<<(VV_ * HH_ / 4 + 255) / 256, 256, 0, stream>>>(embed, embed_bf, VV_ * HH_ / 4);
  cvt_bf16<<<(BB_ * SS_ * HH_ / 4 + 255) / 256, 256, 0, stream>>>(enc, enc_bf, BB_ * SS_ * HH_ / 4);
  cvt_bf16<<<(2304 * HH_ / 4 + 255) / 256, 256, 0, stream>>>(wih, wih_bf, 2304 * HH_ / 4);
  cvt_bf16<<<(2304 * HH_ / 4 + 255) / 256, 256, 0, stream>>>(whh, whh_bf, 2304 * HH_ / 4);
  cvt_bf16<<<(BB_ * HH_ / 4 + 255) / 256, 256, 0, stream>>>(hidden, hid_bf, BB_ * HH_ / 4);

  // 2) step inputs ws[tau*32+b][k]
  build_ws<<<(MM_ * HH_ + 255) / 256, 256, 0, stream>>>(dec, teacher, embed, ws_bf);

  // 3) GI = ws @ Wih^T  (bias added later in gru_step): M=1152, N=2304, K=768
  gemm_bt<<<dim3(2304 / 128, MM_ / 128), 256, 0, stream>>>(ws_bf, wih_bf, GI, 2304, 2304);

  // 4) encg (for p_gen context term)
  enc_gate<<<BB_ * SS_ / 4, 256, 0, stream>>>(enc, wgen, encg);

  // 5) serial GRU scan: 36 tiny MFMA steps
  for (int tau = 0; tau < TT_; ++tau) {
    const __bf16* Aprev = (tau == 0) ? hid_bf : (A_h + (size_t)(tau - 1) * HH_);
    size_t pstride = (tau == 0) ? (size_t)HH_ : (size_t)TT_ * HH_;
    const float* Hprev = (tau == 0) ? hidden : (H_all + (size_t)(tau - 1) * BB_ * HH_);
    gru_step<<<24, 256, 0, stream>>>(Aprev, pstride, Hprev, whh_bf,
                                     GI + (size_t)tau * BB_ * 2304, bih, bhh,
                                     H_all + (size_t)tau * BB_ * HH_, A_h, tau);
  }

  // 6) attention scores + masked softmax + p_gen
  attn_gemm<<<BB_ * 4, 256, 0, stream>>>(A_h, enc_bf, E);
  softmax_pg<<<MM_, 256, 0, stream>>>(E, x, encg, ws_bf, A_h, wgen, wgenb, attn, pg);

  // 7) vocab logits into d_out: M=1152, N=30522, K=768
  gemm_bt<<<dim3((VV_ + 127) / 128, MM_ / 128), 256, 0, stream>>>(A_h, embed_bf, out, VV_, VV_);

  // 8) softmax over V + mix with p_gen (in-place), then pointer scatter
  rowstat<<<MM_, 256, 0, stream>>>(out, rm, rs);
  finalize<<<dim3((VV_ + 255) / 256, MM_), 256, 0, stream>>>(out, rm, rs, pg);
  scatter_ctx<<<MM_, 256, 0, stream>>>(out, attn, pg, x);
}

// Round 2
// 976.626 us; speedup vs baseline: 1.0739x; 1.0739x over previous
//
#include <hip/hip_runtime.h>
#include <math.h>

// B=32, S=256, NU=4, ML=9, H=768, V=30522; T = NU*ML = 36; M = B*T = 1152.
#define BB_ 32
#define SS_ 256
#define HH_ 768
#define VV_ 30522
#define TT_ 36
#define MM_ 1152
#define NBLK_GRU 48

typedef __bf16 bf16x8 __attribute__((ext_vector_type(8)));
typedef __bf16 bf16x4 __attribute__((ext_vector_type(4)));
typedef float f32x4 __attribute__((ext_vector_type(4)));

__device__ __forceinline__ float sigmoidf_(float x) { return 1.f / (1.f + expf(-x)); }

// async global->LDS, 16B per lane; LDS dest is wave-uniform base + lane*16
__device__ __forceinline__ void async_load16(const void* g, void* l) {
  __builtin_amdgcn_global_load_lds(
      (const __attribute__((address_space(1))) void*)g,
      (__attribute__((address_space(3))) void*)l, 16, 0, 0);
}

// ---------------- fp32 -> bf16 bulk convert ----------------
__global__ __launch_bounds__(256) void cvt_bf16(const float* __restrict__ s,
                                                __bf16* __restrict__ d, int n4) {
  int i = blockIdx.x * 256 + threadIdx.x;
  if (i < n4) {
    float4 v = reinterpret_cast<const float4*>(s)[i];
    bf16x4 o;
    o[0] = (__bf16)v.x; o[1] = (__bf16)v.y; o[2] = (__bf16)v.z; o[3] = (__bf16)v.w;
    reinterpret_cast<bf16x4*>(d)[i] = o;
  }
}

// ---------------- build step inputs ws[tau*32+b][k] (bf16) ----------------
__global__ __launch_bounds__(256) void build_ws(const float* __restrict__ dec,
                                                const int* __restrict__ teacher,
                                                const float* __restrict__ embed,
                                                __bf16* __restrict__ wsbf) {
  int idx = blockIdx.x * 256 + threadIdx.x;
  if (idx >= MM_ * HH_) return;
  int m = idx / HH_, k = idx - m * HH_;
  int tau = m >> 5, b = m & 31;
  int u = tau / 9, tt = tau - u * 9;
  float v;
  if (tt == 0) v = dec[((size_t)b * 4 + u) * HH_ + k];
  else v = embed[(size_t)teacher[(b * 4 + u) * 9 + tt - 1] * HH_ + k];
  wsbf[idx] = (__bf16)v;
}

// ---------------- encg[b][s] = enc[b][s][:] . wgen[1536:2304] ----------------
__global__ __launch_bounds__(256) void enc_gate(const float* __restrict__ enc,
                                                const float* __restrict__ wgen,
                                                float* __restrict__ encg) {
  int row = blockIdx.x * 4 + (threadIdx.x >> 6);
  int lane = threadIdx.x & 63;
  const float* er = enc + (size_t)row * HH_;
  float ssum = 0.f;
#pragma unroll
  for (int i = 0; i < 12; ++i) ssum += er[i * 64 + lane] * wgen[1536 + i * 64 + lane];
  for (int off = 32; off; off >>= 1) ssum += __shfl_down(ssum, off);
  if (lane == 0) encg[row] = ssum;
}

// ---------------- m97-style bf16 GEMM: C[M][ldC] = A[M][768] * B[N][768]^T ----------------
// MODE 0: store fp32. MODE 1: store exp(min(c,60)) fp32 + atomic row-sum of exp.
template <int MODE>
__global__ __launch_bounds__(256) void gemm_bt2(const __bf16* __restrict__ A,
                                                const __bf16* __restrict__ Bm,
                                                float* __restrict__ C,
                                                float* __restrict__ rowsum,
                                                int Nreal, int ldC) {
  __shared__ __bf16 As[128 * 32];
  __shared__ __bf16 Bs[128 * 32];
  const int tid = threadIdx.x;
  const int lane = tid & 63, wave = tid >> 6;
  const int wm = wave >> 1, wn = wave & 1;
  const int q = lane >> 4, ln = lane & 15;
  const int m0 = blockIdx.y * 128, n0 = blockIdx.x * 128;
  // staging geometry: per wave, 2 issues x (16 rows x 4 lanes) per array
  const int srow = (wave << 5) + (lane >> 2);   // wave*32 + lane/4
  const int kc = lane & 3;                       // 16B chunk within 32-col row
  const size_t aoff = (size_t)(m0 + srow) * HH_ + kc * 8;
  const size_t aoff2 = aoff + 16 * HH_;
  int br1 = n0 + srow;      if (br1 >= Nreal) br1 = Nreal - 1;
  int br2 = n0 + srow + 16; if (br2 >= Nreal) br2 = Nreal - 1;
  __bf16* lA1 = &As[srow * 32 + kc * 8];
  __bf16* lA2 = &As[(srow + 16) * 32 + kc * 8];
  __bf16* lB1 = &Bs[srow * 32 + kc * 8];
  __bf16* lB2 = &Bs[(srow + 16) * 32 + kc * 8];
  f32x4 acc[4][4] = {};
  for (int kb = 0; kb < 24; ++kb) {
    const int k0 = kb << 5;
    async_load16(A + aoff + k0, lA1);
    async_load16(A + aoff2 + k0, lA2);
    async_load16(Bm + (size_t)br1 * HH_ + kc * 8 + k0, lB1);
    async_load16(Bm + (size_t)br2 * HH_ + kc * 8 + k0, lB2);
    __syncthreads();
    bf16x8 af[4], bfr[4];
#pragma unroll
    for (int mi = 0; mi < 4; ++mi)
      af[mi] = *reinterpret_cast<const bf16x8*>(&As[(wm * 64 + mi * 16 + ln) * 32 + q * 8]);
#pragma unroll
    for (int ni = 0; ni < 4; ++ni)
      bfr[ni] = *reinterpret_cast<const bf16x8*>(&Bs[(wn * 64 + ni * 16 + ln) * 32 + q * 8]);
#pragma unroll
    for (int mi = 0; mi < 4; ++mi)
#pragma unroll
      for (int ni = 0; ni < 4; ++ni)
        acc[mi][ni] = __builtin_amdgcn_mfma_f32_16x16x32_bf16(af[mi], bfr[ni], acc[mi][ni], 0, 0, 0);
    __syncthreads();
  }
#pragma unroll
  for (int mi = 0; mi < 4; ++mi)
#pragma unroll
    for (int r2 = 0; r2 < 4; ++r2) {
      const int m = m0 + wm * 64 + mi * 16 + q * 4 + r2;
      if (MODE == 0) {
#pragma unroll
        for (int ni = 0; ni < 4; ++ni) {
          int n = n0 + wn * 64 + ni * 16 + ln;
          if (n < Nreal) C[(size_t)m * ldC + n] = acc[mi][ni][r2];
        }
      } else {
        float part = 0.f;
#pragma unroll
        for (int ni = 0; ni < 4; ++ni) {
          int n = n0 + wn * 64 + ni * 16 + ln;
          float e = expf(fminf(acc[mi][ni][r2], 60.f));
          if (n < Nreal) { C[(size_t)m * ldC + n] = e; part += e; }
        }
#pragma unroll
        for (int o = 1; o < 16; o <<= 1) part += __shfl_xor(part, o);
        if (ln == 0) atomicAdd(rowsum + m, part);
      }
    }
}

// ---------------- persistent GRU scan: 36 steps, manual grid barrier ----------------
__global__ __launch_bounds__(128) void gru_scan(const __bf16* __restrict__ hid_bf,
                                                const float* __restrict__ H0,
                                                const __bf16* __restrict__ Whh,
                                                const float* __restrict__ GI,
                                                const float* __restrict__ bih,
                                                const float* __restrict__ bhh,
                                                float* __restrict__ H_all,
                                                __bf16* __restrict__ Ah,
                                                unsigned* arrive, unsigned* release) {
  const int tid = threadIdx.x, lane = tid & 63;
  const int mi = tid >> 6;              // 2 waves: b-tile
  const int q = lane >> 4, ln = lane & 15;
  const int jH = blockIdx.x * 16 + ln;  // this block's 16 hidden dims
  const __bf16* brow0 = Whh + (size_t)jH * HH_;
  const __bf16* brow1 = brow0 + (size_t)768 * HH_;
  const __bf16* brow2 = brow0 + (size_t)1536 * HH_;
  const float bir = bih[jH], biz = bih[jH + 768], bin_ = bih[jH + 1536];
  const float bhr = bhh[jH], bhz = bhh[jH + 768], bhn = bhh[jH + 1536];
  for (int tau = 0; tau < TT_; ++tau) {
    const __bf16* arow = tau ? (Ah + ((size_t)(mi * 16 + ln) * TT_ + (tau - 1)) * HH_)
                             : (hid_bf + (size_t)(mi * 16 + ln) * HH_);
    const float* Hp = tau ? (H_all + (size_t)(tau - 1) * BB_ * HH_) : H0;
    const float* GIt = GI + (size_t)tau * BB_ * 2304;
    // prefetch gate inputs (independent of MFMA chain)
    float gir[4], giz[4], gin[4], hp[4];
#pragma unroll
    for (int r2 = 0; r2 < 4; ++r2) {
      int b = mi * 16 + q * 4 + r2;
      const float* gi = GIt + (size_t)b * 2304;
      gir[r2] = gi[jH]; giz[r2] = gi[jH + 768]; gin[r2] = gi[jH + 1536];
      hp[r2] = Hp[(size_t)b * HH_ + jH];
    }
    f32x4 a0 = {}, a1 = {}, a2 = {};
#pragma unroll 4
    for (int kb = 0; kb < 24; ++kb) {
      int k0 = kb * 32 + q * 8;
      bf16x8 a = *reinterpret_cast<const bf16x8*>(arow + k0);
      bf16x8 b0 = *reinterpret_cast<const bf16x8*>(brow0 + k0);
      bf16x8 b1 = *reinterpret_cast<const bf16x8*>(brow1 + k0);
      bf16x8 b2 = *reinterpret_cast<const bf16x8*>(brow2 + k0);
      a0 = __builtin_amdgcn_mfma_f32_16x16x32_bf16(a, b0, a0, 0, 0, 0);
      a1 = __builtin_amdgcn_mfma_f32_16x16x32_bf16(a, b1, a1, 0, 0, 0);
      a2 = __builtin_amdgcn_mfma_f32_16x16x32_bf16(a, b2, a2, 0, 0, 0);
    }
    float* Ho = H_all + (size_t)tau * BB_ * HH_;
#pragma unroll
    for (int r2 = 0; r2 < 4; ++r2) {
      int b = mi * 16 + q * 4 + r2;
      float r = sigmoidf_(gir[r2] + bir + a0[r2] + bhr);
      float z = sigmoidf_(giz[r2] + biz + a1[r2] + bhz);
      float n = tanhf(gin[r2] + bin_ + r * (a2[r2] + bhn));
      float h = (1.f - z) * n + z * hp[r2];
      Ho[(size_t)b * HH_ + jH] = h;
      Ah[((size_t)b * TT_ + tau) * HH_ + jH] = (__bf16)h;
    }
    if (tau < TT_ - 1) {
      __syncthreads();   // drains vmcnt: all waves' stores are in L2 before arrive
      if (tid == 0) {
        unsigned v = __hip_atomic_fetch_add(arrive, 1u, __ATOMIC_ACQ_REL,
                                            __HIP_MEMORY_SCOPE_AGENT) + 1u;
        if (v == (unsigned)(NBLK_GRU * (tau + 1)))
          __hip_atomic_fetch_add(release, 1u, __ATOMIC_ACQ_REL, __HIP_MEMORY_SCOPE_AGENT);
        int spin = 0;
        while (__hip_atomic_load(release, __ATOMIC_ACQUIRE, __HIP_MEMORY_SCOPE_AGENT) <
               (unsigned)(tau + 1)) {
          __builtin_amdgcn_s_sleep(2);
          if (++spin > (1 << 24)) break;   // safety valve: fail loud, don't wedge the GPU
        }
      }
      __syncthreads();
    }
  }
}

// ---------------- attention scores E[b*36+tau][s] (batched MFMA) ----------------
__global__ __launch_bounds__(256) void attn_gemm(const __bf16* __restrict__ Ah,
                                                 const __bf16* __restrict__ encb,
                                                 float* __restrict__ E) {
  int b = blockIdx.x >> 2, stile = blockIdx.x & 3;
  int wave = threadIdx.x >> 6, lane = threadIdx.x & 63;
  int q = lane >> 4, ln = lane & 15;
  int s = stile * 64 + wave * 16 + ln;
  const __bf16* brow = encb + ((size_t)b * SS_ + s) * HH_;
  const __bf16* arow[3];
#pragma unroll
  for (int mt = 0; mt < 3; ++mt) {
    int tau = mt * 16 + ln; if (tau > 35) tau = 35;
    arow[mt] = Ah + ((size_t)b * TT_ + tau) * HH_;
  }
  f32x4 acc[3] = {};
#pragma unroll 4
  for (int kb = 0; kb < 24; ++kb) {
    int k0 = kb * 32 + q * 8;
    bf16x8 bb = *reinterpret_cast<const bf16x8*>(brow + k0);
#pragma unroll
    for (int mt = 0; mt < 3; ++mt) {
      bf16x8 aa = *reinterpret_cast<const bf16x8*>(arow[mt] + k0);
      acc[mt] = __builtin_amdgcn_mfma_f32_16x16x32_bf16(aa, bb, acc[mt], 0, 0, 0);
    }
  }
#pragma unroll
  for (int mt = 0; mt < 3; ++mt)
#pragma unroll
    for (int r2 = 0; r2 < 4; ++r2) {
      int tau = mt * 16 + q * 4 + r2;
      if (tau < 36) E[((size_t)b * TT_ + tau) * SS_ + s] = acc[mt][r2];
    }
}

// ---------------- masked softmax over S + p_gen ----------------
__global__ __launch_bounds__(256) void softmax_pg(const float* __restrict__ E,
                                                  const int* __restrict__ x,
                                                  const float* __restrict__ encg,
                                                  const __bf16* __restrict__ wsbf,
                                                  const __bf16* __restrict__ Ah,
                                                  const float* __restrict__ wgen,
                                                  const float* __restrict__ wgenb,
                                                  float* __restrict__ attn,
                                                  float* __restrict__ pg) {
  int m = blockIdx.x;
  int b = m / TT_, tau = m - b * TT_;
  int m_in = tau * 32 + b;
  int t = threadIdx.x;
  __shared__ float red[256];
  __shared__ float r1[256], r2[256], r3[256];
  float e = E[(size_t)m * SS_ + t];
  if (x[b * SS_ + t] == 0) e = -1000000000.0f;
  red[t] = e; __syncthreads();
  for (int off = 128; off; off >>= 1) {
    if (t < off) red[t] = fmaxf(red[t], red[t + off]);
    __syncthreads();
  }
  float mx = red[0];
  float p = expf(e - mx);
  float dsum = 0.f;
#pragma unroll
  for (int i = 0; i < 3; ++i) {
    int k = t + i * 256;
    dsum += (float)wsbf[(size_t)m_in * HH_ + k] * wgen[k];
    dsum += (float)Ah[(size_t)m * HH_ + k] * wgen[768 + k];
  }
  float pe = p * encg[b * SS_ + t];
  r1[t] = p; r2[t] = pe; r3[t] = dsum; __syncthreads();
  for (int off = 128; off; off >>= 1) {
    if (t < off) { r1[t] += r1[t + off]; r2[t] += r2[t + off]; r3[t] += r3[t + off]; }
    __syncthreads();
  }
  float Z = r1[0];
  attn[(size_t)m * SS_ + t] = p / Z;
  if (t == 0) pg[m] = sigmoidf_(r3[0] + r2[0] / Z + wgenb[0]);
}

// ---------------- finalize: out = pg/Z * exp_vals (in place) ----------------
__global__ __launch_bounds__(256) void finalize(float* __restrict__ C,
                                                const float* __restrict__ rowsum,
                                                const float* __restrict__ pg) {
  int m = blockIdx.y;
  float scale = pg[m] / rowsum[m];
  int base_i = blockIdx.x * 2048;
  size_t rowb = (size_t)m * VV_;
#pragma unroll
  for (int j = 0; j < 8; ++j) {
    int i = base_i + j * 256 + threadIdx.x;
    if (i < VV_) C[rowb + i] *= scale;
  }
}

// ---------------- pointer scatter: out[m][x[b][s]] += (1-pg)*attn[m][s] ----------------
__global__ __launch_bounds__(256) void scatter_ctx(float* __restrict__ C,
                                                   const float* __restrict__ attn,
                                                   const float* __restrict__ pg,
                                                   const int* __restrict__ x) {
  int m = blockIdx.x, s = threadIdx.x;
  int b = m / TT_;
  float v = (1.f - pg[m]) * attn[(size_t)m * SS_ + s];
  int col = x[b * SS_ + s];
  atomicAdd(C + (size_t)m * VV_ + col, v);
}

extern "C" void kernel_launch(void* const* d_in, const int* in_sizes, int n_in,
                              void* d_out, int out_size, void* d_ws, size_t ws_size,
                              hipStream_t stream) {
  const int*   x       = (const int*)d_in[0];
  const float* dec     = (const float*)d_in[1];
  const float* enc     = (const float*)d_in[2];
  const float* hidden  = (const float*)d_in[3];
  const int*   teacher = (const int*)d_in[5];
  const float* embed   = (const float*)d_in[6];
  const float* wih     = (const float*)d_in[7];
  const float* whh     = (const float*)d_in[8];
  const float* bih     = (const float*)d_in[9];
  const float* bhh     = (const float*)d_in[10];
  const float* wgen    = (const float*)d_in[11];
  const float* wgenb   = (const float*)d_in[12];
  float* out = (float*)d_out;

  // workspace layout (~86 MB)
  char* w = (char*)d_ws;
  __bf16* embed_bf = (__bf16*)w;  w += (size_t)VV_ * HH_ * 2;
  __bf16* enc_bf   = (__bf16*)w;  w += (size_t)BB_ * SS_ * HH_ * 2;
  __bf16* wih_bf   = (__bf16*)w;  w += (size_t)2304 * HH_ * 2;
  __bf16* whh_bf   = (__bf16*)w;  w += (size_t)2304 * HH_ * 2;
  __bf16* ws_bf    = (__bf16*)w;  w += (size_t)MM_ * HH_ * 2;
  __bf16* hid_bf   = (__bf16*)w;  w += (size_t)BB_ * HH_ * 2;
  __bf16* A_h      = (__bf16*)w;  w += (size_t)MM_ * HH_ * 2;
  float*  H_all    = (float*)w;   w += (size_t)TT_ * BB_ * HH_ * 4;
  float*  GI       = (float*)w;   w += (size_t)MM_ * 2304 * 4;
  float*  E        = (float*)w;   w += (size_t)MM_ * SS_ * 4;
  float*  attn     = (float*)w;   w += (size_t)MM_ * SS_ * 4;
  float*  encg     = (float*)w;   w += (size_t)BB_ * SS_ * 4;
  float*  pg       = (float*)w;   w += 8192;
  char*   ctl      = w;           w += 8192;   // rowsum[1152] fp32 + barrier counters
  float*    rowsum  = (float*)ctl;
  unsigned* arrive  = (unsigned*)(ctl + 6144);
  unsigned* release = (unsigned*)(ctl + 6144 + 64);

  // 0) zero rowsum + barrier counters (ws is poisoned 0xAA before every call)
  hipMemsetAsync(ctl, 0, 8192, stream);

  // 1) conversions to bf16
  cvt_bf16<<<(VV_ * HH_ / 4 + 255) / 256, 256, 0, stream>>>(embed, embed_bf, VV_ * HH_ / 4);
  cvt_bf16<<<(BB_ * SS_ * HH_ / 4 + 255) / 256, 256, 0, stream>>>(enc, enc_bf, BB_ * SS_ * HH_ / 4);
  cvt_bf16<<<(2304 * HH_ / 4 + 255) / 256, 256, 0, stream>>>(wih, wih_bf, 2304 * HH_ / 4);
  cvt_bf16<<<(2304 * HH_ / 4 + 255) / 256, 256, 0, stream>>>(whh, whh_bf, 2304 * HH_ / 4);
  cvt_bf16<<<(BB_ * HH_ / 4 + 255) / 256, 256, 0, stream>>>(hidden, hid_bf, BB_ * HH_ / 4);

  // 2) step inputs
  build_ws<<<(MM_ * HH_ + 255) / 256, 256, 0, stream>>>(dec, teacher, embed, ws_bf);

  // 3) GI = ws @ Wih^T : M=1152, N=2304, K=768
  gemm_bt2<0><<<dim3(2304 / 128, MM_ / 128), 256, 0, stream>>>(ws_bf, wih_bf, GI, nullptr, 2304, 2304);

  // 4) encg
  enc_gate<<<BB_ * SS_ / 4, 256, 0, stream>>>(enc, wgen, encg);

  // 5) persistent GRU scan (one launch, grid barrier between 36 steps)
  gru_scan<<<NBLK_GRU, 128, 0, stream>>>(hid_bf, hidden, whh_bf, GI, bih, bhh,
                                         H_all, A_h, arrive, release);

  // 6) attention + masked softmax + p_gen
  attn_gemm<<<BB_ * 4, 256, 0, stream>>>(A_h, enc_bf, E);
  softmax_pg<<<MM_, 256, 0, stream>>>(E, x, encg, ws_bf, A_h, wgen, wgenb, attn, pg);

  // 7) vocab logits -> exp into d_out + atomic row sums: M=1152, N=30522
  gemm_bt2<1><<<dim3((VV_ + 127) / 128, MM_ / 128), 256, 0, stream>>>(A_h, embed_bf, out, rowsum, VV_, VV_);

  // 8) scale by pg/Z in place, then pointer scatter
  finalize<<<dim3((VV_ + 2047) / 2048, MM_), 256, 0, stream>>>(out, rowsum, pg);
  scatter_ctx<<<MM_, 256, 0, stream>>>(out, attn, pg, x);
}

// Round 3
// 782.116 us; speedup vs baseline: 1.3410x; 1.2487x over previous
//
#include <hip/hip_runtime.h>
#include <math.h>

// B=32, S=256, NU=4, ML=9, H=768, V=30522; T = NU*ML = 36; M = B*T = 1152.
#define BB_ 32
#define SS_ 256
#define HH_ 768
#define VV_ 30522
#define TT_ 36
#define MM_ 1152
#define NBLK_GRU 48

typedef __bf16 bf16x8 __attribute__((ext_vector_type(8)));
typedef __bf16 bf16x4 __attribute__((ext_vector_type(4)));
typedef float f32x4 __attribute__((ext_vector_type(4)));

__device__ __forceinline__ float sigmoidf_(float x) { return 1.f / (1.f + expf(-x)); }

// async global->LDS, 16B per lane; LDS dest is wave-uniform base + lane*16
__device__ __forceinline__ void async_load16(const void* g, void* l) {
  __builtin_amdgcn_global_load_lds(
      (const __attribute__((address_space(1))) void*)g,
      (__attribute__((address_space(3))) void*)l, 16, 0, 0);
}

// ---------------- fp32 -> bf16 bulk convert ----------------
__global__ __launch_bounds__(256) void cvt_bf16(const float* __restrict__ s,
                                                __bf16* __restrict__ d, int n4) {
  int i = blockIdx.x * 256 + threadIdx.x;
  if (i < n4) {
    float4 v = reinterpret_cast<const float4*>(s)[i];
    bf16x4 o;
    o[0] = (__bf16)v.x; o[1] = (__bf16)v.y; o[2] = (__bf16)v.z; o[3] = (__bf16)v.w;
    reinterpret_cast<bf16x4*>(d)[i] = o;
  }
}

// ---------------- build step inputs ws[tau*32+b][k] (bf16) ----------------
__global__ __launch_bounds__(256) void build_ws(const float* __restrict__ dec,
                                                const int* __restrict__ teacher,
                                                const float* __restrict__ embed,
                                                __bf16* __restrict__ wsbf) {
  int idx = blockIdx.x * 256 + threadIdx.x;
  if (idx >= MM_ * HH_) return;
  int m = idx / HH_, k = idx - m * HH_;
  int tau = m >> 5, b = m & 31;
  int u = tau / 9, tt = tau - u * 9;
  float v;
  if (tt == 0) v = dec[((size_t)b * 4 + u) * HH_ + k];
  else v = embed[(size_t)teacher[(b * 4 + u) * 9 + tt - 1] * HH_ + k];
  wsbf[idx] = (__bf16)v;
}

// ---------------- encg[b][s] = enc[b][s][:] . wgen[1536:2304] ----------------
__global__ __launch_bounds__(256) void enc_gate(const float* __restrict__ enc,
                                                const float* __restrict__ wgen,
                                                float* __restrict__ encg) {
  int row = blockIdx.x * 4 + (threadIdx.x >> 6);
  int lane = threadIdx.x & 63;
  const float* er = enc + (size_t)row * HH_;
  float ssum = 0.f;
#pragma unroll
  for (int i = 0; i < 12; ++i) ssum += er[i * 64 + lane] * wgen[1536 + i * 64 + lane];
  for (int off = 32; off; off >>= 1) ssum += __shfl_down(ssum, off);
  if (lane == 0) encg[row] = ssum;
}

// ---------------- m97-style bf16 GEMM: C[M][ldC] = A[M][768] * B[N][768]^T ----------------
// MODE 0: store fp32. MODE 1: store exp(min(c,60)) fp32 + atomic row-sum of exp.
template <int MODE>
__global__ __launch_bounds__(256) void gemm_bt2(const __bf16* __restrict__ A,
                                                const __bf16* __restrict__ Bm,
                                                float* __restrict__ C,
                                                float* __restrict__ rowsum,
                                                int Nreal, int ldC) {
  __shared__ __bf16 As[128 * 32];
  __shared__ __bf16 Bs[128 * 32];
  const int tid = threadIdx.x;
  const int lane = tid & 63, wave = tid >> 6;
  const int wm = wave >> 1, wn = wave & 1;
  const int q = lane >> 4, ln = lane & 15;
  const int m0 = blockIdx.y * 128, n0 = blockIdx.x * 128;
  const int srow = (wave << 5) + (lane >> 2);
  const int kc = lane & 3;
  const size_t aoff = (size_t)(m0 + srow) * HH_ + kc * 8;
  const size_t aoff2 = aoff + 16 * HH_;
  int br1 = n0 + srow;      if (br1 >= Nreal) br1 = Nreal - 1;
  int br2 = n0 + srow + 16; if (br2 >= Nreal) br2 = Nreal - 1;
  __bf16* lA1 = &As[srow * 32 + kc * 8];
  __bf16* lA2 = &As[(srow + 16) * 32 + kc * 8];
  __bf16* lB1 = &Bs[srow * 32 + kc * 8];
  __bf16* lB2 = &Bs[(srow + 16) * 32 + kc * 8];
  f32x4 acc[4][4] = {};
  for (int kb = 0; kb < 24; ++kb) {
    const int k0 = kb << 5;
    async_load16(A + aoff + k0, lA1);
    async_load16(A + aoff2 + k0, lA2);
    async_load16(Bm + (size_t)br1 * HH_ + kc * 8 + k0, lB1);
    async_load16(Bm + (size_t)br2 * HH_ + kc * 8 + k0, lB2);
    __syncthreads();
    bf16x8 af[4], bfr[4];
#pragma unroll
    for (int mi = 0; mi < 4; ++mi)
      af[mi] = *reinterpret_cast<const bf16x8*>(&As[(wm * 64 + mi * 16 + ln) * 32 + q * 8]);
#pragma unroll
    for (int ni = 0; ni < 4; ++ni)
      bfr[ni] = *reinterpret_cast<const bf16x8*>(&Bs[(wn * 64 + ni * 16 + ln) * 32 + q * 8]);
#pragma unroll
    for (int mi = 0; mi < 4; ++mi)
#pragma unroll
      for (int ni = 0; ni < 4; ++ni)
        acc[mi][ni] = __builtin_amdgcn_mfma_f32_16x16x32_bf16(af[mi], bfr[ni], acc[mi][ni], 0, 0, 0);
    __syncthreads();
  }
#pragma unroll
  for (int mi = 0; mi < 4; ++mi)
#pragma unroll
    for (int r2 = 0; r2 < 4; ++r2) {
      const int m = m0 + wm * 64 + mi * 16 + q * 4 + r2;
      if (MODE == 0) {
#pragma unroll
        for (int ni = 0; ni < 4; ++ni) {
          int n = n0 + wn * 64 + ni * 16 + ln;
          if (n < Nreal) C[(size_t)m * ldC + n] = acc[mi][ni][r2];
        }
      } else {
        float part = 0.f;
#pragma unroll
        for (int ni = 0; ni < 4; ++ni) {
          int n = n0 + wn * 64 + ni * 16 + ln;
          float e = expf(fminf(acc[mi][ni][r2], 60.f));
          if (n < Nreal) { C[(size_t)m * ldC + n] = e; part += e; }
        }
#pragma unroll
        for (int o = 1; o < 16; o <<= 1) part += __shfl_xor(part, o);
        if (ln == 0) atomicAdd(rowsum + m, part);
      }
    }
}

// ---------------- persistent GRU scan v2 ----------------
// 48 blocks x 128. Whh slice (48 rows x 768) XOR-swizzled in LDS; h carried in
// registers; barrier = per-block flag words (no RMW contention) + vector spin.
__global__ __launch_bounds__(128) void gru_scan(const __bf16* __restrict__ hid_bf,
                                                const float* __restrict__ H0,
                                                const __bf16* __restrict__ Whh,
                                                const float* __restrict__ GI,
                                                const float* __restrict__ bih,
                                                const float* __restrict__ bhh,
                                                __bf16* __restrict__ Ah,
                                                unsigned* __restrict__ flags) {
  __shared__ __bf16 WhhS[48 * HH_];   // 73,728 B
  const int tid = threadIdx.x, lane = tid & 63;
  const int mi = tid >> 6;            // wave id: b-tile (0:,16:)
  const int q = lane >> 4, ln = lane & 15;
  const int jH = blockIdx.x * 16 + ln;
  // stage Whh rows [g*768 + blk*16 + jl] -> LDS row g*16+jl, 16B chunk cs at cs^(row&7)
  for (int i = tid; i < 48 * 96; i += 128) {
    int row = i / 96, cs = i - row * 96;
    int g = row >> 4, jl = row & 15;
    bf16x8 v = *reinterpret_cast<const bf16x8*>(
        &Whh[((size_t)(g * 768 + blockIdx.x * 16 + jl)) * HH_ + cs * 8]);
    *reinterpret_cast<bf16x8*>(&WhhS[row * HH_ + ((cs ^ (row & 7)) * 8)]) = v;
  }
  const float bir = bih[jH], biz = bih[jH + 768], bin_ = bih[jH + 1536];
  const float bhr = bhh[jH], bhz = bhh[jH + 768], bhn = bhh[jH + 1536];
  // carry h in registers: this thread owns (b = mi*16+q*4+r2, jH)
  float hc[4];
#pragma unroll
  for (int r2 = 0; r2 < 4; ++r2)
    hc[r2] = H0[(size_t)(mi * 16 + q * 4 + r2) * HH_ + jH];
  const __bf16* w0 = &WhhS[(0 + ln) * HH_];
  const __bf16* w1 = &WhhS[(16 + ln) * HH_];
  const __bf16* w2 = &WhhS[(32 + ln) * HH_];
  const int swz = (ln & 7) * 8;       // XOR swizzle in bf16 units (chunk^= ln&7)
  __syncthreads();
  for (int tau = 0; tau < TT_; ++tau) {
    const __bf16* arow = tau ? (Ah + ((size_t)(mi * 16 + ln) * TT_ + (tau - 1)) * HH_)
                             : (hid_bf + (size_t)(mi * 16 + ln) * HH_);
    const float* GIt = GI + (size_t)tau * BB_ * 2304;
    float gir[4], giz[4], gin[4];
#pragma unroll
    for (int r2 = 0; r2 < 4; ++r2) {
      const float* gi = GIt + (size_t)(mi * 16 + q * 4 + r2) * 2304;
      gir[r2] = gi[jH]; giz[r2] = gi[jH + 768]; gin[r2] = gi[jH + 1536];
    }
    f32x4 a0 = {}, a1 = {}, a2 = {};
#pragma unroll 4
    for (int kb = 0; kb < 24; ++kb) {
      int k0 = kb * 32 + q * 8;
      int kl = (k0 ^ swz);
      bf16x8 a = *reinterpret_cast<const bf16x8*>(arow + k0);
      bf16x8 b0 = *reinterpret_cast<const bf16x8*>(w0 + kl);
      bf16x8 b1 = *reinterpret_cast<const bf16x8*>(w1 + kl);
      bf16x8 b2 = *reinterpret_cast<const bf16x8*>(w2 + kl);
      a0 = __builtin_amdgcn_mfma_f32_16x16x32_bf16(a, b0, a0, 0, 0, 0);
      a1 = __builtin_amdgcn_mfma_f32_16x16x32_bf16(a, b1, a1, 0, 0, 0);
      a2 = __builtin_amdgcn_mfma_f32_16x16x32_bf16(a, b2, a2, 0, 0, 0);
    }
#pragma unroll
    for (int r2 = 0; r2 < 4; ++r2) {
      int b = mi * 16 + q * 4 + r2;
      float r = sigmoidf_(gir[r2] + bir + a0[r2] + bhr);
      float z = sigmoidf_(giz[r2] + biz + a1[r2] + bhz);
      float n = tanhf(gin[r2] + bin_ + r * (a2[r2] + bhn));
      float h = (1.f - z) * n + z * hc[r2];
      hc[r2] = h;
      Ah[((size_t)b * TT_ + tau) * HH_ + jH] = (__bf16)h;
    }
    if (tau < TT_ - 1) {
      __syncthreads();   // both waves' Ah stores drained (vmcnt) before release
      if (tid == 0)
        __hip_atomic_store(&flags[(size_t)blockIdx.x * 16], (unsigned)(tau + 1),
                           __ATOMIC_RELEASE, __HIP_MEMORY_SCOPE_AGENT);
      const unsigned tgt = (unsigned)(tau + 1);
      int ok = 0, spin = 0;
      while (!ok) {
        unsigned v = (lane < NBLK_GRU)
            ? __hip_atomic_load(&flags[(size_t)lane * 16], __ATOMIC_ACQUIRE,
                                __HIP_MEMORY_SCOPE_AGENT)
            : tgt;
        ok = __all((int)(v >= tgt));
        if (!ok) {
          __builtin_amdgcn_s_sleep(1);
          if (++spin > (1 << 20)) break;   // fail loud, don't wedge
        }
      }
    }
  }
}

// ---------------- attention scores E[b*36+tau][s] (batched MFMA) ----------------
__global__ __launch_bounds__(256) void attn_gemm(const __bf16* __restrict__ Ah,
                                                 const __bf16* __restrict__ encb,
                                                 float* __restrict__ E) {
  int b = blockIdx.x >> 2, stile = blockIdx.x & 3;
  int wave = threadIdx.x >> 6, lane = threadIdx.x & 63;
  int q = lane >> 4, ln = lane & 15;
  int s = stile * 64 + wave * 16 + ln;
  const __bf16* brow = encb + ((size_t)b * SS_ + s) * HH_;
  const __bf16* arow[3];
#pragma unroll
  for (int mt = 0; mt < 3; ++mt) {
    int tau = mt * 16 + ln; if (tau > 35) tau = 35;
    arow[mt] = Ah + ((size_t)b * TT_ + tau) * HH_;
  }
  f32x4 acc[3] = {};
#pragma unroll 4
  for (int kb = 0; kb < 24; ++kb) {
    int k0 = kb * 32 + q * 8;
    bf16x8 bb = *reinterpret_cast<const bf16x8*>(brow + k0);
#pragma unroll
    for (int mt = 0; mt < 3; ++mt) {
      bf16x8 aa = *reinterpret_cast<const bf16x8*>(arow[mt] + k0);
      acc[mt] = __builtin_amdgcn_mfma_f32_16x16x32_bf16(aa, bb, acc[mt], 0, 0, 0);
    }
  }
#pragma unroll
  for (int mt = 0; mt < 3; ++mt)
#pragma unroll
    for (int r2 = 0; r2 < 4; ++r2) {
      int tau = mt * 16 + q * 4 + r2;
      if (tau < 36) E[((size_t)b * TT_ + tau) * SS_ + s] = acc[mt][r2];
    }
}

// ---------------- masked softmax over S + p_gen ----------------
__global__ __launch_bounds__(256) void softmax_pg(const float* __restrict__ E,
                                                  const int* __restrict__ x,
                                                  const float* __restrict__ encg,
                                                  const __bf16* __restrict__ wsbf,
                                                  const __bf16* __restrict__ Ah,
                                                  const float* __restrict__ wgen,
                                                  const float* __restrict__ wgenb,
                                                  float* __restrict__ attn,
                                                  float* __restrict__ pg) {
  int m = blockIdx.x;
  int b = m / TT_, tau = m - b * TT_;
  int m_in = tau * 32 + b;
  int t = threadIdx.x;
  __shared__ float red[256];
  __shared__ float r1[256], r2[256], r3[256];
  float e = E[(size_t)m * SS_ + t];
  if (x[b * SS_ + t] == 0) e = -1000000000.0f;
  red[t] = e; __syncthreads();
  for (int off = 128; off; off >>= 1) {
    if (t < off) red[t] = fmaxf(red[t], red[t + off]);
    __syncthreads();
  }
  float mx = red[0];
  float p = expf(e - mx);
  float dsum = 0.f;
#pragma unroll
  for (int i = 0; i < 3; ++i) {
    int k = t + i * 256;
    dsum += (float)wsbf[(size_t)m_in * HH_ + k] * wgen[k];
    dsum += (float)Ah[(size_t)m * HH_ + k] * wgen[768 + k];
  }
  float pe = p * encg[b * SS_ + t];
  r1[t] = p; r2[t] = pe; r3[t] = dsum; __syncthreads();
  for (int off = 128; off; off >>= 1) {
    if (t < off) { r1[t] += r1[t + off]; r2[t] += r2[t + off]; r3[t] += r3[t + off]; }
    __syncthreads();
  }
  float Z = r1[0];
  attn[(size_t)m * SS_ + t] = p / Z;
  if (t == 0) pg[m] = sigmoidf_(r3[0] + r2[0] / Z + wgenb[0]);
}

// ---------------- finalize: out = pg/Z * exp_vals (in place) ----------------
__global__ __launch_bounds__(256) void finalize(float* __restrict__ C,
                                                const float* __restrict__ rowsum,
                                                const float* __restrict__ pg) {
  int m = blockIdx.y;
  float scale = pg[m] / rowsum[m];
  int base_i = blockIdx.x * 2048;
  size_t rowb = (size_t)m * VV_;
#pragma unroll
  for (int j = 0; j < 8; ++j) {
    int i = base_i + j * 256 + threadIdx.x;
    if (i < VV_) C[rowb + i] *= scale;
  }
}

// ---------------- pointer scatter ----------------
__global__ __launch_bounds__(256) void scatter_ctx(float* __restrict__ C,
                                                   const float* __restrict__ attn,
                                                   const float* __restrict__ pg,
                                                   const int* __restrict__ x) {
  int m = blockIdx.x, s = threadIdx.x;
  int b = m / TT_;
  float v = (1.f - pg[m]) * attn[(size_t)m * SS_ + s];
  int col = x[b * SS_ + s];
  atomicAdd(C + (size_t)m * VV_ + col, v);
}

extern "C" void kernel_launch(void* const* d_in, const int* in_sizes, int n_in,
                              void* d_out, int out_size, void* d_ws, size_t ws_size,
                              hipStream_t stream) {
  const int*   x       = (const int*)d_in[0];
  const float* dec     = (const float*)d_in[1];
  const float* enc     = (const float*)d_in[2];
  const float* hidden  = (const float*)d_in[3];
  const int*   teacher = (const int*)d_in[5];
  const float* embed   = (const float*)d_in[6];
  const float* wih     = (const float*)d_in[7];
  const float* whh     = (const float*)d_in[8];
  const float* bih     = (const float*)d_in[9];
  const float* bhh     = (const float*)d_in[10];
  const float* wgen    = (const float*)d_in[11];
  const float* wgenb   = (const float*)d_in[12];
  float* out = (float*)d_out;

  char* w = (char*)d_ws;
  __bf16* embed_bf = (__bf16*)w;  w += (size_t)VV_ * HH_ * 2;
  __bf16* enc_bf   = (__bf16*)w;  w += (size_t)BB_ * SS_ * HH_ * 2;
  __bf16* wih_bf   = (__bf16*)w;  w += (size_t)2304 * HH_ * 2;
  __bf16* whh_bf   = (__bf16*)w;  w += (size_t)2304 * HH_ * 2;
  __bf16* ws_bf    = (__bf16*)w;  w += (size_t)MM_ * HH_ * 2;
  __bf16* hid_bf   = (__bf16*)w;  w += (size_t)BB_ * HH_ * 2;
  __bf16* A_h      = (__bf16*)w;  w += (size_t)MM_ * HH_ * 2;
  float*  GI       = (float*)w;   w += (size_t)MM_ * 2304 * 4;
  float*  E        = (float*)w;   w += (size_t)MM_ * SS_ * 4;
  float*  attn     = (float*)w;   w += (size_t)MM_ * SS_ * 4;
  float*  encg     = (float*)w;   w += (size_t)BB_ * SS_ * 4;
  float*  pg       = (float*)w;   w += 8192;
  char*   ctl      = w;           w += 8192;   // rowsum[1152] + flags[48*16]
  float*    rowsum = (float*)ctl;
  unsigned* flags  = (unsigned*)(ctl + 4864);

  // 0) zero rowsum + flags (ws is re-poisoned 0xAA before every call)
  hipMemsetAsync(ctl, 0, 8192, stream);

  // 1) conversions to bf16
  cvt_bf16<<<(VV_ * HH_ / 4 + 255) / 256, 256, 0, stream>>>(embed, embed_bf, VV_ * HH_ / 4);
  cvt_bf16<<<(BB_ * SS_ * HH_ / 4 + 255) / 256, 256, 0, stream>>>(enc, enc_bf, BB_ * SS_ * HH_ / 4);
  cvt_bf16<<<(2304 * HH_ / 4 + 255) / 256, 256, 0, stream>>>(wih, wih_bf, 2304 * HH_ / 4);
  cvt_bf16<<<(2304 * HH_ / 4 + 255) / 256, 256, 0, stream>>>(whh, whh_bf, 2304 * HH_ / 4);
  cvt_bf16<<<(BB_ * HH_ / 4 + 255) / 256, 256, 0, stream>>>(hidden, hid_bf, BB_ * HH_ / 4);

  // 2) step inputs
  build_ws<<<(MM_ * HH_ + 255) / 256, 256, 0, stream>>>(dec, teacher, embed, ws_bf);

  // 3) GI = ws @ Wih^T : M=1152, N=2304, K=768
  gemm_bt2<0><<<dim3(2304 / 128, MM_ / 128), 256, 0, stream>>>(ws_bf, wih_bf, GI, nullptr, 2304, 2304);

  // 4) encg
  enc_gate<<<BB_ * SS_ / 4, 256, 0, stream>>>(enc, wgen, encg);

  // 5) persistent GRU scan (contention-free flag barrier)
  gru_scan<<<NBLK_GRU, 128, 0, stream>>>(hid_bf, hidden, whh_bf, GI, bih, bhh, A_h, flags);

  // 6) attention + masked softmax + p_gen
  attn_gemm<<<BB_ * 4, 256, 0, stream>>>(A_h, enc_bf, E);
  softmax_pg<<<MM_, 256, 0, stream>>>(E, x, encg, ws_bf, A_h, wgen, wgenb, attn, pg);

  // 7) vocab logits -> exp into d_out + atomic row sums
  gemm_bt2<1><<<dim3((VV_ + 127) / 128, MM_ / 128), 256, 0, stream>>>(A_h, embed_bf, out, rowsum, VV_, VV_);

  // 8) scale by pg/Z in place, then pointer scatter
  finalize<<<dim3((VV_ + 2047) / 2048, MM_), 256, 0, stream>>>(out, rowsum, pg);
  scatter_ctx<<<MM_, 256, 0, stream>>>(out, attn, pg, x);
}